// Round 3
// baseline (399.214 us; speedup 1.0000x reference)
//
#include <hip/hip_runtime.h>

// Epsilon-greedy action selection.
//   q_vals:       [BATCH, N_ACTIONS] f32
//   rand_u:       [BATCH] f32
//   rand_actions: [BATCH] i32
//   out:          [BATCH] i32 = rand_u < eps ? rand_actions : argmax(q_vals, axis=1)
//
// MEASUREMENT ROUND: kernel body is byte-identical to round 2 (persistent
// waves, 16 rows/wave, 2-deep pipeline). kernel_launch launches it TWICE
// (idempotent: the second launch recomputes the same output). The dur_us
// delta vs round 2 isolates one (warm) kernel execution time, separating
// kernel time from the harness's ~160us poison-fill dispatches that dominate
// the timed region.

#define N_ACTIONS 512
#define EPSILON 0.05f
#define ROWS_PER_WAVE 16
#define WAVES_PER_BLOCK 4
#define ROWS_PER_BLOCK (ROWS_PER_WAVE * WAVES_PER_BLOCK)

__global__ __launch_bounds__(256) void
SelectAction_64862596104471_kernel(const float* __restrict__ q_vals,
                                   const float* __restrict__ rand_u,
                                   const int* __restrict__ rand_actions,
                                   int* __restrict__ out,
                                   int batch) {
    const int lane = threadIdx.x & 63;
    const long long wave = (long long)blockIdx.x * WAVES_PER_BLOCK + (threadIdx.x >> 6);
    const long long row0 = wave * ROWS_PER_WAVE;
    if (row0 >= batch) return;

    long long rem = (long long)batch - row0;
    const int nrows = (rem < ROWS_PER_WAVE) ? (int)rem : ROWS_PER_WAVE;

    // 128 float4 per row.
    const float4* q = (const float4*)q_vals + row0 * (N_ACTIONS / 4);

    // Pipeline stage 0: loads for row row0.
    float4 a = q[lane];
    float4 b = q[lane + 64];

    for (int r = 0; r < nrows; ++r) {
        // Prefetch next row before the dependent shuffle chain below.
        float4 na = a, nb = b;
        if (r + 1 < nrows) {
            const float4* qn = q + (long long)(r + 1) * (N_ACTIONS / 4);
            na = qn[lane];
            nb = qn[lane + 64];
        }

        // Lane-local argmax in ascending element-index order; strict '>'
        // keeps the lowest index on ties (jnp.argmax semantics).
        float best = a.x;
        int bidx = 4 * lane;
        if (a.y > best) { best = a.y; bidx = 4 * lane + 1; }
        if (a.z > best) { best = a.z; bidx = 4 * lane + 2; }
        if (a.w > best) { best = a.w; bidx = 4 * lane + 3; }
        if (b.x > best) { best = b.x; bidx = 256 + 4 * lane; }
        if (b.y > best) { best = b.y; bidx = 256 + 4 * lane + 1; }
        if (b.z > best) { best = b.z; bidx = 256 + 4 * lane + 2; }
        if (b.w > best) { best = b.w; bidx = 256 + 4 * lane + 3; }

        // 64-lane butterfly: prefer higher value; on exact tie prefer the
        // lower element index.
        #pragma unroll
        for (int off = 32; off > 0; off >>= 1) {
            float ov = __shfl_xor(best, off, 64);
            int oi = __shfl_xor(bidx, off, 64);
            if (ov > best || (ov == best && oi < bidx)) {
                best = ov;
                bidx = oi;
            }
        }

        if (lane == 0) {
            const long long row = row0 + r;
            out[row] = (rand_u[row] < EPSILON) ? rand_actions[row] : bidx;
        }

        a = na;
        b = nb;
    }
}

extern "C" void kernel_launch(void* const* d_in, const int* in_sizes, int n_in,
                              void* d_out, int out_size, void* d_ws, size_t ws_size,
                              hipStream_t stream) {
    const float* q_vals = (const float*)d_in[0];
    const float* rand_u = (const float*)d_in[1];
    const int* rand_actions = (const int*)d_in[2];
    int* out = (int*)d_out;

    const int batch = in_sizes[1];  // rand_u element count == BATCH

    const int blocks = (batch + ROWS_PER_BLOCK - 1) / ROWS_PER_BLOCK;
    // Launch twice: identical, idempotent work. dur_us(R3) - dur_us(R2)
    // measures one warm kernel execution.
    SelectAction_64862596104471_kernel<<<blocks, 256, 0, stream>>>(
        q_vals, rand_u, rand_actions, out, batch);
    SelectAction_64862596104471_kernel<<<blocks, 256, 0, stream>>>(
        q_vals, rand_u, rand_actions, out, batch);
}

// Round 4
// 355.623 us; speedup vs baseline: 1.1226x; 1.1226x over previous
//
#include <hip/hip_runtime.h>

// Epsilon-greedy action selection.
//   q_vals:       [BATCH, N_ACTIONS] f32
//   rand_u:       [BATCH] f32
//   rand_actions: [BATCH] i32
//   out:          [BATCH] i32 = rand_u < eps ? rand_actions : argmax(q_vals, axis=1)
//
// FINAL: persistent waves, 16 contiguous rows per wave, 2-deep software
// pipeline. One 64-lane wave covers a 512-float row with two coalesced
// float4 loads (1 KiB per load instruction); row r+1's loads issue before
// row r's 12-shuffle argmax chain so memory stays in flight. 2048 blocks x
// 256 threads = 8192 waves = 32/CU.
//
// Measured (R3 double-launch probe): one warm execution = 44.9 us vs a
// ~40-43 us single-pass HBM roofline for the mandatory 270 MB read
// (~90-95% of achievable BW). The remaining ~309 us of harness dur_us is
// fixed overhead (1 GiB 0xAA poison fills at ~160 us each + restores) and
// is not addressable from kernel code.

#define N_ACTIONS 512
#define EPSILON 0.05f
#define ROWS_PER_WAVE 16
#define WAVES_PER_BLOCK 4
#define ROWS_PER_BLOCK (ROWS_PER_WAVE * WAVES_PER_BLOCK)

__global__ __launch_bounds__(256) void
SelectAction_64862596104471_kernel(const float* __restrict__ q_vals,
                                   const float* __restrict__ rand_u,
                                   const int* __restrict__ rand_actions,
                                   int* __restrict__ out,
                                   int batch) {
    const int lane = threadIdx.x & 63;
    const long long wave = (long long)blockIdx.x * WAVES_PER_BLOCK + (threadIdx.x >> 6);
    const long long row0 = wave * ROWS_PER_WAVE;
    if (row0 >= batch) return;

    long long rem = (long long)batch - row0;
    const int nrows = (rem < ROWS_PER_WAVE) ? (int)rem : ROWS_PER_WAVE;

    // 128 float4 per row.
    const float4* q = (const float4*)q_vals + row0 * (N_ACTIONS / 4);

    // Pipeline stage 0: loads for the first row.
    float4 a = q[lane];
    float4 b = q[lane + 64];

    for (int r = 0; r < nrows; ++r) {
        // Prefetch next row before the dependent shuffle chain below.
        float4 na = a, nb = b;
        if (r + 1 < nrows) {
            const float4* qn = q + (long long)(r + 1) * (N_ACTIONS / 4);
            na = qn[lane];
            nb = qn[lane + 64];
        }

        // Lane-local argmax in ascending element-index order; strict '>'
        // keeps the lowest index on ties (jnp.argmax semantics).
        float best = a.x;
        int bidx = 4 * lane;
        if (a.y > best) { best = a.y; bidx = 4 * lane + 1; }
        if (a.z > best) { best = a.z; bidx = 4 * lane + 2; }
        if (a.w > best) { best = a.w; bidx = 4 * lane + 3; }
        if (b.x > best) { best = b.x; bidx = 256 + 4 * lane; }
        if (b.y > best) { best = b.y; bidx = 256 + 4 * lane + 1; }
        if (b.z > best) { best = b.z; bidx = 256 + 4 * lane + 2; }
        if (b.w > best) { best = b.w; bidx = 256 + 4 * lane + 3; }

        // 64-lane butterfly: prefer higher value; on exact tie prefer the
        // lower element index.
        #pragma unroll
        for (int off = 32; off > 0; off >>= 1) {
            float ov = __shfl_xor(best, off, 64);
            int oi = __shfl_xor(bidx, off, 64);
            if (ov > best || (ov == best && oi < bidx)) {
                best = ov;
                bidx = oi;
            }
        }

        if (lane == 0) {
            const long long row = row0 + r;
            // 16 consecutive rows share a 64B line of rand_u / rand_actions.
            out[row] = (rand_u[row] < EPSILON) ? rand_actions[row] : bidx;
        }

        a = na;
        b = nb;
    }
}

extern "C" void kernel_launch(void* const* d_in, const int* in_sizes, int n_in,
                              void* d_out, int out_size, void* d_ws, size_t ws_size,
                              hipStream_t stream) {
    const float* q_vals = (const float*)d_in[0];
    const float* rand_u = (const float*)d_in[1];
    const int* rand_actions = (const int*)d_in[2];
    int* out = (int*)d_out;

    const int batch = in_sizes[1];  // rand_u element count == BATCH

    const int blocks = (batch + ROWS_PER_BLOCK - 1) / ROWS_PER_BLOCK;
    SelectAction_64862596104471_kernel<<<blocks, 256, 0, stream>>>(
        q_vals, rand_u, rand_actions, out, batch);
}